// Round 1
// baseline (126.096 us; speedup 1.0000x reference)
//
#include <hip/hip_runtime.h>
#include <math.h>

// Problem constants (match reference)
#define NF 256          // features
#define NB 64           // batch
#define M_CON 515       // 2N+3 constraints
static constexpr double EPS_Q  = 1e-4;
static constexpr double SIGMA  = 0.1;
static constexpr double CAPC   = 10.0;
static constexpr int    ITERS  = 20;

__device__ __forceinline__ double wave_sum(double v) {
    #pragma unroll
    for (int off = 32; off > 0; off >>= 1)
        v += __shfl_xor(v, off, 64);
    return v;
}
__device__ __forceinline__ double wave_min(double v) {
    #pragma unroll
    for (int off = 32; off > 0; off >>= 1)
        v = fmin(v, __shfl_xor(v, off, 64));
    return v;
}

// One wave per batch item. Lane j owns features j, j+64, j+128, j+192.
// Constraint layout: k0: sum(x)<=C ; lo_i: -x_i<=0 ; hi_i: x_i<=1 ;
// kA: m.x <= rhs_fair+1 ; kB: -m.x <= -rhs_fair.
// Schur complement M = diag(EPS + d_lo + d_hi) + d0*11^T + (dA+dB)*mm^T
// -> rank-2 Woodbury solve, O(N).
__global__ __launch_bounds__(64)
void pdipm_kernel(const float* __restrict__ xin,
                  const int* __restrict__ male,
                  float* __restrict__ out) {
    const int b = blockIdx.x;
    const int lane = threadIdx.x;

    double p[4], mf[4], x[4];
    double s_lo[4], s_hi[4], z_lo[4], z_hi[4];
    double msum_p = 0.0;
    #pragma unroll
    for (int k = 0; k < 4; ++k) {
        const int f = lane + 64 * k;
        p[k]  = -(double)xin[b * NF + f];
        mf[k] = (double)male[f];
        msum_p += mf[k];
        x[k] = 0.0;
        s_lo[k] = 1.0; s_hi[k] = 1.0;
        z_lo[k] = 1.0; z_hi[k] = 1.0;
    }
    const double nm = wave_sum(msum_p);
    const double rhs_fair = CAPC * nm / 256.0;
    const double hA = rhs_fair + 1.0;
    const double hB = -rhs_fair;

    // Scalar constraints: wave-uniform replicated state.
    double s0 = 1.0, z0 = 1.0, sA = 1.0, zA = 1.0, sB = 1.0, zB = 1.0;

    for (int it = 0; it < ITERS; ++it) {
        // ---- Phase A: mu, sum(x), sum(m*x) ----
        double musum_p = 0.0, Sx_p = 0.0, Smx_p = 0.0;
        #pragma unroll
        for (int k = 0; k < 4; ++k) {
            musum_p += s_lo[k] * z_lo[k] + s_hi[k] * z_hi[k];
            Sx_p  += x[k];
            Smx_p += mf[k] * x[k];
        }
        const double musum = wave_sum(musum_p) + s0 * z0 + sA * zA + sB * zB;
        const double Sx  = wave_sum(Sx_p);
        const double Smx = wave_sum(Smx_p);
        const double smu = SIGMA * (musum / (double)M_CON);

        // ---- scalar-constraint residuals (uniform) ----
        const double rs0 = s0 + Sx - CAPC;
        const double rsA = sA + Smx - hA;
        const double rsB = sB - Smx - hB;
        const double rc0 = s0 * z0 - smu;
        const double rcA = sA * zA - smu;
        const double rcB = sB * zB - smu;
        const double d0 = z0 / s0, dA = zA / sA, dB = zB / sB;
        const double w0 = (-rc0 + z0 * rs0) / s0;
        const double wA = (-rcA + zA * rsA) / sA;
        const double wB = (-rcB + zB * rsB) / sB;
        const double wAmB = wA - wB;
        const double zAmB = zA - zB;

        // ---- per-feature residuals, diagonal, rhs; Woodbury partials ----
        double rs_lo[4], rs_hi[4], rc_lo[4], rc_hi[4], Dg[4], y[4];
        double t1_p = 0.0, t2_p = 0.0, s11_p = 0.0, s12_p = 0.0;
        #pragma unroll
        for (int k = 0; k < 4; ++k) {
            rs_lo[k] = s_lo[k] - x[k];             // s + (-x) - 0
            rs_hi[k] = s_hi[k] + x[k] - 1.0;       // s + x - 1
            rc_lo[k] = s_lo[k] * z_lo[k] - smu;
            rc_hi[k] = s_hi[k] * z_hi[k] - smu;
            const double d_lo = z_lo[k] / s_lo[k];
            const double d_hi = z_hi[k] / s_hi[k];
            const double w_lo = (-rc_lo[k] + z_lo[k] * rs_lo[k]) / s_lo[k];
            const double w_hi = (-rc_hi[k] + z_hi[k] * rs_hi[k]) / s_hi[k];
            const double gtz = z0 - z_lo[k] + z_hi[k] + mf[k] * zAmB;
            const double rx  = EPS_Q * x[k] + p[k] + gtz;
            const double gtw = w0 - w_lo + w_hi + mf[k] * wAmB;
            const double rhs = -(rx + gtw);
            Dg[k] = EPS_Q + d_lo + d_hi;
            const double invD = 1.0 / Dg[k];
            y[k] = rhs * invD;
            t1_p  += y[k];
            t2_p  += mf[k] * y[k];
            s11_p += invD;
            s12_p += mf[k] * invD;
        }
        const double t1  = wave_sum(t1_p);
        const double t2  = wave_sum(t2_p);
        const double s11 = wave_sum(s11_p);
        const double s12 = wave_sum(s12_p);   // == s22 since m is 0/1

        // ---- 2x2 capacitance solve: (C^-1 + U^T D^-1 U) c = t ----
        const double a  = d0;
        const double bb = dA + dB;
        const double k11 = 1.0 / a + s11;
        const double k22 = 1.0 / bb + s12;
        const double det = k11 * k22 - s12 * s12;
        const double c1 = (k22 * t1 - s12 * t2) / det;
        const double c2 = (k11 * t2 - s12 * t1) / det;

        // ---- dx and its reductions ----
        double dx[4];
        double Sdx_p = 0.0, Smdx_p = 0.0;
        #pragma unroll
        for (int k = 0; k < 4; ++k) {
            dx[k] = y[k] - (c1 + c2 * mf[k]) / Dg[k];
            Sdx_p  += dx[k];
            Smdx_p += mf[k] * dx[k];
        }
        const double Sdx  = wave_sum(Sdx_p);
        const double Smdx = wave_sum(Smdx_p);

        // ---- ds, dz ----
        const double ds0 = -rs0 - Sdx;
        const double dsA = -rsA - Smdx;
        const double dsB = -rsB + Smdx;
        const double dz0 = (-rc0 - z0 * ds0) / s0;
        const double dzA = (-rcA - zA * dsA) / sA;
        const double dzB = (-rcB - zB * dsB) / sB;

        const double INF = INFINITY;
        double amin_p = INF;
        double ds_lo[4], ds_hi[4], dz_lo[4], dz_hi[4];
        #pragma unroll
        for (int k = 0; k < 4; ++k) {
            ds_lo[k] = -rs_lo[k] + dx[k];   // -(rs) - (G dx)_lo, (G dx)_lo = -dx
            ds_hi[k] = -rs_hi[k] - dx[k];
            dz_lo[k] = (-rc_lo[k] - z_lo[k] * ds_lo[k]) / s_lo[k];
            dz_hi[k] = (-rc_hi[k] - z_hi[k] * ds_hi[k]) / s_hi[k];
            amin_p = fmin(amin_p, ds_lo[k] < 0.0 ? -s_lo[k] / ds_lo[k] : INF);
            amin_p = fmin(amin_p, ds_hi[k] < 0.0 ? -s_hi[k] / ds_hi[k] : INF);
            amin_p = fmin(amin_p, dz_lo[k] < 0.0 ? -z_lo[k] / dz_lo[k] : INF);
            amin_p = fmin(amin_p, dz_hi[k] < 0.0 ? -z_hi[k] / dz_hi[k] : INF);
        }
        double amin = wave_min(amin_p);
        amin = fmin(amin, ds0 < 0.0 ? -s0 / ds0 : INF);
        amin = fmin(amin, dsA < 0.0 ? -sA / dsA : INF);
        amin = fmin(amin, dsB < 0.0 ? -sB / dsB : INF);
        amin = fmin(amin, dz0 < 0.0 ? -z0 / dz0 : INF);
        amin = fmin(amin, dzA < 0.0 ? -zA / dzA : INF);
        amin = fmin(amin, dzB < 0.0 ? -zB / dzB : INF);
        const double alpha = fmin(1.0, 0.99 * amin);

        // ---- update ----
        #pragma unroll
        for (int k = 0; k < 4; ++k) {
            x[k]    += alpha * dx[k];
            s_lo[k] += alpha * ds_lo[k];
            s_hi[k] += alpha * ds_hi[k];
            z_lo[k] += alpha * dz_lo[k];
            z_hi[k] += alpha * dz_hi[k];
        }
        s0 += alpha * ds0; z0 += alpha * dz0;
        sA += alpha * dsA; zA += alpha * dzA;
        sB += alpha * dsB; zB += alpha * dzB;
    }

    #pragma unroll
    for (int k = 0; k < 4; ++k)
        out[b * NF + lane + 64 * k] = (float)x[k];
}

extern "C" void kernel_launch(void* const* d_in, const int* in_sizes, int n_in,
                              void* d_out, int out_size, void* d_ws, size_t ws_size,
                              hipStream_t stream) {
    const float* xin  = (const float*)d_in[0];   // [64, 256] fp32
    const int*   male = (const int*)d_in[1];     // [256] int32
    float* out = (float*)d_out;                  // [64, 256] fp32
    pdipm_kernel<<<NB, 64, 0, stream>>>(xin, male, out);
}

// Round 4
// 97.862 us; speedup vs baseline: 1.2885x; 1.2885x over previous
//
#include <hip/hip_runtime.h>
#include <math.h>

// Problem constants (match reference)
#define NF 256          // features
#define NB 64           // batch
#define M_CON 515       // 2N+3 constraints
static constexpr double EPS_Q  = 1e-4;
static constexpr double SIGMA  = 0.1;
static constexpr double CAPC   = 10.0;
static constexpr int    ITERS  = 20;

// Fast fp64 reciprocal: v_rcp_f64 seed (~2^-26 rel) + 1 Newton-Raphson step
// -> ~2^-52 rel, fp64 noise floor. Replaces the ~13-instr IEEE div sequence
// with rcp + 2 FMA. All denominators here are strictly nonzero.
__device__ __forceinline__ double drcp(double x) {
    double r = __builtin_amdgcn_rcp(x);
    r = fma(r, fma(-x, r, 1.0), r);
    return r;
}

__device__ __forceinline__ double wave_sum(double v) {
    #pragma unroll
    for (int off = 32; off > 0; off >>= 1)
        v += __shfl_xor(v, off, 64);
    return v;
}
__device__ __forceinline__ double wave_min(double v) {
    #pragma unroll
    for (int off = 32; off > 0; off >>= 1)
        v = fmin(v, __shfl_xor(v, off, 64));
    return v;
}

// One wave per batch item. Lane j owns features j, j+64, j+128, j+192.
// Constraints: row0: sum(x)<=C ; lo_i: -x_i<=0 ; hi_i: x_i<=1 ;
// rowA: m.x <= rhs_fair+1 ; rowB: -m.x <= -rhs_fair.
//
// Exact algebra (verified symbolically, fp64 state):
//   rhs = -(EPS x + p) - G^T phi, phi_r = d_r rs_r + smu/s_r   (G^T z cancels)
//   rhat = -(EPS x + p) + phi_lo - phi_hi = base + smu*dif  (smu split out so
//   t1,t2 partials join the first reduction group: 2 groups/iter, not 4)
//   M = D + d0*11^T + (dA+dB)*mm^T -> rank-2 Woodbury; M^-1 1 = D^-1(a1+a2 m),
//   M^-1 m = D^-1(b1+b2 m) in cancelled closed form.
//   dz = smu/s - z - d*ds.
__global__ __launch_bounds__(64)
void pdipm_kernel(const float* __restrict__ xin,
                  const int* __restrict__ male,
                  float* __restrict__ out) {
    const int b = blockIdx.x;
    const int lane = threadIdx.x;

    double p[4], mf[4], x[4];
    double s_lo[4], s_hi[4], z_lo[4], z_hi[4];
    double msum_p = 0.0;
    #pragma unroll
    for (int k = 0; k < 4; ++k) {
        const int f = lane + 64 * k;
        p[k]  = -(double)xin[b * NF + f];
        mf[k] = (double)male[f];
        msum_p += mf[k];
        x[k] = 0.0;
        s_lo[k] = 1.0; s_hi[k] = 1.0;
        z_lo[k] = 1.0; z_hi[k] = 1.0;
    }
    const double nm = wave_sum(msum_p);
    const double rhs_fair = CAPC * nm * (1.0 / 256.0);
    const double hA = rhs_fair + 1.0;
    const double hB = -rhs_fair;

    // Scalar constraints: wave-uniform replicated state.
    double s0 = 1.0, z0 = 1.0, sA = 1.0, zA = 1.0, sB = 1.0, zB = 1.0;

    for (int it = 0; it < ITERS; ++it) {
        // ---- state reciprocals (ILP-friendly, start of chain) ----
        const double i_s0 = drcp(s0), i_sA = drcp(sA), i_sB = drcp(sB);
        const double d0 = z0 * i_s0, dA = zA * i_sA, dB = zB * i_sB;

        // ---- single merged reduction group: 9 values ----
        double i_slo[4], i_shi[4], d_lo[4], d_hi[4], invD[4];
        double rs_lo[4], rs_hi[4], base[4], dif[4];
        double musum_p = 0.0, Sx_p = 0.0, Smx_p = 0.0, s11_p = 0.0, s12_p = 0.0;
        double t1b_p = 0.0, t1m_p = 0.0, t2b_p = 0.0, t2m_p = 0.0;
        #pragma unroll
        for (int k = 0; k < 4; ++k) {
            musum_p += s_lo[k] * z_lo[k] + s_hi[k] * z_hi[k];
            Sx_p  += x[k];
            Smx_p += mf[k] * x[k];
            i_slo[k] = drcp(s_lo[k]);
            i_shi[k] = drcp(s_hi[k]);
            d_lo[k] = z_lo[k] * i_slo[k];
            d_hi[k] = z_hi[k] * i_shi[k];
            invD[k] = drcp(EPS_Q + d_lo[k] + d_hi[k]);
            rs_lo[k] = s_lo[k] - x[k];             // s + (-x) - 0
            rs_hi[k] = s_hi[k] + x[k] - 1.0;       // s + x - 1
            base[k] = -(EPS_Q * x[k] + p[k]) + d_lo[k] * rs_lo[k] - d_hi[k] * rs_hi[k];
            dif[k]  = i_slo[k] - i_shi[k];
            const double bD = base[k] * invD[k];
            const double dD = dif[k]  * invD[k];
            s11_p += invD[k];
            s12_p += mf[k] * invD[k];
            t1b_p += bD;
            t1m_p += dD;
            t2b_p += mf[k] * bD;
            t2m_p += mf[k] * dD;
        }
        const double musum = wave_sum(musum_p) + s0 * z0 + sA * zA + sB * zB;
        const double Sx  = wave_sum(Sx_p);
        const double Smx = wave_sum(Smx_p);
        const double s11 = wave_sum(s11_p);
        const double s12 = wave_sum(s12_p);   // == s22 since m is 0/1
        const double t1b = wave_sum(t1b_p);
        const double t1m = wave_sum(t1m_p);
        const double t2b = wave_sum(t2b_p);
        const double t2m = wave_sum(t2m_p);
        const double smu = SIGMA * musum * (1.0 / (double)M_CON);

        // ---- scalar residuals, shift coefficients ----
        const double rs0 = s0 + Sx - CAPC;
        const double rsA = sA + Smx - hA;
        const double rsB = sB - Smx - hB;
        const double beta  = d0 * rs0 + smu * i_s0;                       // phi0
        const double gamma = (dA * rsA + smu * i_sA) - (dB * rsB + smu * i_sB);
        const double t1 = t1b + smu * t1m;
        const double t2 = t2b + smu * t2m;

        // ---- 2x2 capacitance algebra (closed-form M^-1 1 / M^-1 m) ----
        const double ia  = drcp(d0);
        const double ibb = drcp(dA + dB);
        const double k11 = ia + s11;
        const double k22 = ibb + s12;
        const double i_det = drcp(k11 * k22 - s12 * s12);
        const double c1 = (k22 * t1 - s12 * t2) * i_det;
        const double c2 = (k11 * t2 - s12 * t1) * i_det;
        const double a1 =  ia * k22 * i_det;
        const double a2 = -ia * s12 * i_det;
        const double b1 = -ibb * s12 * i_det;
        const double b2 =  ibb * k11 * i_det;
        const double C1 = c1 + beta * a1 + gamma * b1;
        const double C2 = c2 + beta * a2 + gamma * b2;

        // ---- per-feature directions + second reduction group (3 values) ----
        double dx[4], ds_lo[4], ds_hi[4], dz_lo[4], dz_hi[4];
        double Sdx_p = 0.0, Smdx_p = 0.0;
        const double INF = INFINITY;
        double amin_p = INF;
        #pragma unroll
        for (int k = 0; k < 4; ++k) {
            const double y = (base[k] + smu * dif[k]) * invD[k];
            dx[k] = y - invD[k] * (C1 + C2 * mf[k]);
            Sdx_p  += dx[k];
            Smdx_p += mf[k] * dx[k];
            ds_lo[k] = -rs_lo[k] + dx[k];   // ds = -rs - G dx, (G dx)_lo = -dx
            ds_hi[k] = -rs_hi[k] - dx[k];
            dz_lo[k] = smu * i_slo[k] - z_lo[k] - d_lo[k] * ds_lo[k];
            dz_hi[k] = smu * i_shi[k] - z_hi[k] - d_hi[k] * ds_hi[k];
            amin_p = fmin(amin_p, ds_lo[k] < 0.0 ? -s_lo[k] * drcp(ds_lo[k]) : INF);
            amin_p = fmin(amin_p, ds_hi[k] < 0.0 ? -s_hi[k] * drcp(ds_hi[k]) : INF);
            amin_p = fmin(amin_p, dz_lo[k] < 0.0 ? -z_lo[k] * drcp(dz_lo[k]) : INF);
            amin_p = fmin(amin_p, dz_hi[k] < 0.0 ? -z_hi[k] * drcp(dz_hi[k]) : INF);
        }
        const double Sdx  = wave_sum(Sdx_p);
        const double Smdx = wave_sum(Smdx_p);
        double amin = wave_min(amin_p);

        // ---- scalar directions + alpha ----
        const double ds0 = -rs0 - Sdx;
        const double dsA = -rsA - Smdx;
        const double dsB = -rsB + Smdx;
        const double dz0 = smu * i_s0 - z0 - d0 * ds0;
        const double dzA = smu * i_sA - zA - dA * dsA;
        const double dzB = smu * i_sB - zB - dB * dsB;
        amin = fmin(amin, ds0 < 0.0 ? -s0 * drcp(ds0) : INF);
        amin = fmin(amin, dsA < 0.0 ? -sA * drcp(dsA) : INF);
        amin = fmin(amin, dsB < 0.0 ? -sB * drcp(dsB) : INF);
        amin = fmin(amin, dz0 < 0.0 ? -z0 * drcp(dz0) : INF);
        amin = fmin(amin, dzA < 0.0 ? -zA * drcp(dzA) : INF);
        amin = fmin(amin, dzB < 0.0 ? -zB * drcp(dzB) : INF);
        const double alpha = fmin(1.0, 0.99 * amin);

        // ---- update ----
        #pragma unroll
        for (int k = 0; k < 4; ++k) {
            x[k]    += alpha * dx[k];
            s_lo[k] += alpha * ds_lo[k];
            s_hi[k] += alpha * ds_hi[k];
            z_lo[k] += alpha * dz_lo[k];
            z_hi[k] += alpha * dz_hi[k];
        }
        s0 += alpha * ds0; z0 += alpha * dz0;
        sA += alpha * dsA; zA += alpha * dzA;
        sB += alpha * dsB; zB += alpha * dzB;
    }

    #pragma unroll
    for (int k = 0; k < 4; ++k)
        out[b * NF + lane + 64 * k] = (float)x[k];
}

extern "C" void kernel_launch(void* const* d_in, const int* in_sizes, int n_in,
                              void* d_out, int out_size, void* d_ws, size_t ws_size,
                              hipStream_t stream) {
    const float* xin  = (const float*)d_in[0];   // [64, 256] fp32
    const int*   male = (const int*)d_in[1];     // [256] int32
    float* out = (float*)d_out;                  // [64, 256] fp32
    pdipm_kernel<<<NB, 64, 0, stream>>>(xin, male, out);
}

// Round 5
// 79.825 us; speedup vs baseline: 1.5796x; 1.2260x over previous
//
#include <hip/hip_runtime.h>
#include <math.h>

// Problem constants (match reference)
#define NF 256          // features
#define NB 64           // batch
#define M_CON 515       // 2N+3 constraints
static constexpr double EPS_Q  = 1e-4;
static constexpr double SIGMA  = 0.1;
static constexpr double CAPC   = 10.0;
static constexpr int    ITERS  = 20;

// Fast fp64 reciprocal: v_rcp_f64 seed + 1 NR step -> ~fp64 noise floor.
__device__ __forceinline__ double drcp(double x) {
    double r = __builtin_amdgcn_rcp(x);
    r = fma(r, fma(-x, r, 1.0), r);
    return r;
}

// Fused 4-way butterfly sum: 8 ds ops per level issued back-to-back so the
// ~120cyc swizzle latency is paid once per level, not per value.
__device__ __forceinline__ void wave_sum4(double& a, double& b, double& c, double& d) {
    #pragma unroll
    for (int off = 32; off > 0; off >>= 1) {
        a += __shfl_xor(a, off, 64);
        b += __shfl_xor(b, off, 64);
        c += __shfl_xor(c, off, 64);
        d += __shfl_xor(d, off, 64);
    }
}
// Fused sum + max butterfly (group 2).
__device__ __forceinline__ void wave_summax(double& s, double& m) {
    #pragma unroll
    for (int off = 32; off > 0; off >>= 1) {
        s += __shfl_xor(s, off, 64);
        m  = fmax(m, __shfl_xor(m, off, 64));
    }
}

// One wave per batch item. Lane j owns features j, j+64, j+128, j+192.
// Constraints: row0: sum(x)<=C ; lo_i: -x_i<=0 ; hi_i: x_i<=1 ;
// rowA: m.x <= rhs_fair+1 ; rowB: -m.x <= -rhs_fair.
//
// Exact-identity restructure (fp64 trajectory == round-4 kernel, verified
// algebra: passed at absmax 2.06e-7):
//  * rs scales by (1-alpha) each step  -> rs0/rsA/rsB/rs_lo/rs_hi tracked.
//  * s.dz + z.ds = -rc  =>  musum' = musum(1-a+a*sigma) + a^2*Sum(ds*dz)
//    -> smu known at loop top; group1 = {s11,s12,t1,t2} only.
//  * Sdx = t1 - C1*s11 - C2*s12 ; Smdx = t2 - (C1+C2)*s12  (no reduction).
//  * alpha = min(1, 0.99/max(rmax,0.99)), rmax = max(-ds/s, -dz/z): s-side
//    ratios reuse i_s (mul+max, no div); group2 = fused {Sdsdz, rmax}.
__global__ __launch_bounds__(64)
void pdipm_kernel(const float* __restrict__ xin,
                  const int* __restrict__ male,
                  float* __restrict__ out) {
    const int b = blockIdx.x;
    const int lane = threadIdx.x;

    double e[4], mf[4], x[4];                 // e = -(EPS*x + p) tracked
    double s_lo[4], s_hi[4], z_lo[4], z_hi[4];
    double rs_lo[4], rs_hi[4];
    double msum_p = 0.0;
    #pragma unroll
    for (int k = 0; k < 4; ++k) {
        const int f = lane + 64 * k;
        const double pv = -(double)xin[b * NF + f];
        mf[k] = (double)male[f];
        msum_p += mf[k];
        e[k] = -pv;                            // x=0 -> e = -p
        x[k] = 0.0;
        s_lo[k] = 1.0; s_hi[k] = 1.0;
        z_lo[k] = 1.0; z_hi[k] = 1.0;
        rs_lo[k] = 1.0;                        // s - x = 1
        rs_hi[k] = 0.0;                        // s + x - 1 = 0
    }
    double nm = msum_p;
    #pragma unroll
    for (int off = 32; off > 0; off >>= 1) nm += __shfl_xor(nm, off, 64);
    const double rhs_fair = CAPC * nm * (1.0 / 256.0);

    // Scalar-constraint state (wave-uniform).
    double s0 = 1.0, z0 = 1.0, sA = 1.0, zA = 1.0, sB = 1.0, zB = 1.0;
    double rs0 = 1.0 - CAPC;                   // s0 + 0 - C
    double rsA = -rhs_fair;                    // 1 + 0 - (rhs_fair+1)
    double rsB = 1.0 + rhs_fair;               // 1 - 0 + rhs_fair
    double musum = (double)M_CON;              // all s=z=1

    for (int it = 0; it < ITERS; ++it) {
        const double smu = SIGMA * musum * (1.0 / (double)M_CON);

        // ---- wave-uniform scalar precompute (hides under group1 latency) ----
        const double i_s0 = drcp(s0), i_sA = drcp(sA), i_sB = drcp(sB);
        const double i_z0 = drcp(z0), i_zA = drcp(zA), i_zB = drcp(zB);
        const double d0 = z0 * i_s0, dA = zA * i_sA, dB = zB * i_sB;
        const double beta  = d0 * rs0 + smu * i_s0;
        const double gamma = (dA * rsA + smu * i_sA) - (dB * rsB + smu * i_sB);
        const double ia  = drcp(d0);
        const double ibb = drcp(dA + dB);

        // ---- group 1: {s11, s12, t1, t2} ----
        double i_slo[4], i_shi[4], d_lo[4], d_hi[4], invD[4], y[4];
        double s11_p = 0.0, s12_p = 0.0, t1_p = 0.0, t2_p = 0.0;
        #pragma unroll
        for (int k = 0; k < 4; ++k) {
            i_slo[k] = drcp(s_lo[k]);
            i_shi[k] = drcp(s_hi[k]);
            d_lo[k] = z_lo[k] * i_slo[k];
            d_hi[k] = z_hi[k] * i_shi[k];
            invD[k] = drcp(EPS_Q + d_lo[k] + d_hi[k]);
            const double rhat = e[k] + d_lo[k] * rs_lo[k] - d_hi[k] * rs_hi[k]
                              + smu * (i_slo[k] - i_shi[k]);
            y[k] = rhat * invD[k];
            s11_p += invD[k];
            s12_p += mf[k] * invD[k];
            t1_p  += y[k];
            t2_p  += mf[k] * y[k];
        }
        wave_sum4(s11_p, s12_p, t1_p, t2_p);
        const double s11 = s11_p, s12 = s12_p, t1 = t1_p, t2 = t2_p;

        // ---- 2x2 capacitance algebra (closed-form M^-1 1 / M^-1 m) ----
        const double k11 = ia + s11;
        const double k22 = ibb + s12;
        const double i_det = drcp(k11 * k22 - s12 * s12);
        const double c1 = (k22 * t1 - s12 * t2) * i_det;
        const double c2 = (k11 * t2 - s12 * t1) * i_det;
        const double a1 =  ia * k22 * i_det;
        const double a2 = -ia * s12 * i_det;
        const double b1 = -ibb * s12 * i_det;
        const double b2 =  ibb * k11 * i_det;
        const double C1 = c1 + beta * a1 + gamma * b1;
        const double C2 = c2 + beta * a2 + gamma * b2;
        const double C1pC2 = C1 + C2;

        // ---- Sdx/Smdx via identities (no reduction) ----
        const double Sdx  = t1 - C1 * s11 - C2 * s12;
        const double Smdx = t2 - C1pC2 * s12;
        const double ds0 = -rs0 - Sdx;
        const double dsA = -rsA - Smdx;
        const double dsB = -rsB + Smdx;
        const double dz0 = smu * i_s0 - z0 - d0 * ds0;
        const double dzA = smu * i_sA - zA - dA * dsA;
        const double dzB = smu * i_sB - zB - dB * dsB;

        // ---- per-feature directions, ratio-max partials, ds.dz partial ----
        double dx[4], ds_lo[4], ds_hi[4], dz_lo[4], dz_hi[4];
        double dsdz_p = 0.0;
        double rmax_p = 0.0;
        #pragma unroll
        for (int k = 0; k < 4; ++k) {
            const double C12 = (mf[k] != 0.0) ? C1pC2 : C1;
            dx[k] = fma(-invD[k], C12, y[k]);
            ds_lo[k] = dx[k] - rs_lo[k];           // ds = -rs - G dx, (G dx)_lo=-dx
            ds_hi[k] = -dx[k] - rs_hi[k];
            dz_lo[k] = smu * i_slo[k] - z_lo[k] - d_lo[k] * ds_lo[k];
            dz_hi[k] = smu * i_shi[k] - z_hi[k] - d_hi[k] * ds_hi[k];
            dsdz_p += ds_lo[k] * dz_lo[k] + ds_hi[k] * dz_hi[k];
            const double i_zlo = drcp(z_lo[k]);
            const double i_zhi = drcp(z_hi[k]);
            const double q1 = -ds_lo[k] * i_slo[k];
            const double q2 = -ds_hi[k] * i_shi[k];
            const double q3 = -dz_lo[k] * i_zlo;
            const double q4 = -dz_hi[k] * i_zhi;
            rmax_p = fmax(rmax_p, fmax(fmax(q1, q2), fmax(q3, q4)));
        }
        wave_summax(dsdz_p, rmax_p);

        // scalar-constraint ratios (wave-uniform, after reduce)
        double rmax = rmax_p;
        rmax = fmax(rmax, fmax(-ds0 * i_s0, -dz0 * i_z0));
        rmax = fmax(rmax, fmax(-dsA * i_sA, -dzA * i_zA));
        rmax = fmax(rmax, fmax(-dsB * i_sB, -dzB * i_zB));
        const double Sdsdz = dsdz_p + ds0 * dz0 + dsA * dzA + dsB * dzB;

        const double alpha = fmin(1.0, 0.99 * drcp(fmax(rmax, 0.99)));
        const double omA = 1.0 - alpha;

        // ---- state update (identities keep rs/musum exact) ----
        #pragma unroll
        for (int k = 0; k < 4; ++k) {
            const double adx = alpha * dx[k];
            x[k] += adx;
            e[k] = fma(-EPS_Q, adx, e[k]);
            s_lo[k] = fma(alpha, ds_lo[k], s_lo[k]);
            s_hi[k] = fma(alpha, ds_hi[k], s_hi[k]);
            z_lo[k] = fma(alpha, dz_lo[k], z_lo[k]);
            z_hi[k] = fma(alpha, dz_hi[k], z_hi[k]);
            rs_lo[k] *= omA;
            rs_hi[k] *= omA;
        }
        s0 = fma(alpha, ds0, s0); z0 = fma(alpha, dz0, z0);
        sA = fma(alpha, dsA, sA); zA = fma(alpha, dzA, zA);
        sB = fma(alpha, dsB, sB); zB = fma(alpha, dzB, zB);
        rs0 *= omA; rsA *= omA; rsB *= omA;
        musum = musum * (1.0 - alpha * (1.0 - SIGMA)) + alpha * alpha * Sdsdz;
    }

    #pragma unroll
    for (int k = 0; k < 4; ++k)
        out[b * NF + lane + 64 * k] = (float)x[k];
}

extern "C" void kernel_launch(void* const* d_in, const int* in_sizes, int n_in,
                              void* d_out, int out_size, void* d_ws, size_t ws_size,
                              hipStream_t stream) {
    const float* xin  = (const float*)d_in[0];   // [64, 256] fp32
    const int*   male = (const int*)d_in[1];     // [256] int32
    float* out = (float*)d_out;                  // [64, 256] fp32
    pdipm_kernel<<<NB, 64, 0, stream>>>(xin, male, out);
}

// Round 6
// 73.352 us; speedup vs baseline: 1.7190x; 1.0882x over previous
//
#include <hip/hip_runtime.h>
#include <math.h>

// Problem constants (match reference)
#define NF 256          // features
#define NB 64           // batch
#define M_CON 515       // 2N+3 constraints
static constexpr double EPS_Q  = 1e-4;
static constexpr double SIGMA  = 0.1;
static constexpr double CAPC   = 10.0;
static constexpr int    ITERS  = 20;

// Fast fp64 reciprocal: v_rcp_f64 seed + 1 NR step -> ~fp64 noise floor.
// Used for everything feeding the Newton direction (precision lesson: fp32/
// low-precision state noise amplifies ~1/mu through the IPM residuals).
__device__ __forceinline__ double drcp(double x) {
    double r = __builtin_amdgcn_rcp(x);
    r = fma(r, fma(-x, r, 1.0), r);
    return r;
}
// Raw rcp (~2^-26 rel): ONLY for step-ratio denominators and alpha — enters
// the trajectory as a ~1e-8 relative step-length perturbation, benign.
__device__ __forceinline__ double drcp_fast(double x) {
    return __builtin_amdgcn_rcp(x);
}

// DPP cross-lane for fp64: two 32-bit v_mov_b32 dpp + reassemble. VALU-speed
// (~10 cyc/level) vs ds_swizzle's ~120 cyc LDS-path latency.
template <int CTRL>
__device__ __forceinline__ double dpp_d(double v) {
    const int lo = __builtin_amdgcn_update_dpp(0, __double2loint(v), CTRL, 0xF, 0xF, true);
    const int hi = __builtin_amdgcn_update_dpp(0, __double2hiint(v), CTRL, 0xF, 0xF, true);
    return __hiloint2double(hi, lo);
}
__device__ __forceinline__ double bcast63(double v) {
    const int lo = __builtin_amdgcn_readlane(__double2loint(v), 63);
    const int hi = __builtin_amdgcn_readlane(__double2hiint(v), 63);
    return __hiloint2double(hi, lo);
}
// Wave64 sum: row_ror 1/2/4/8 (rotation-butterfly within 16-lane rows; every
// lane ends with its row sum), then row_bcast15 + row_bcast31 accumulate row
// sums into lanes 48-63 (bound_ctrl=1 injects 0 for invalid source lanes),
// total read from lane 63 into SGPRs (wave-uniform).
__device__ __forceinline__ double wave_red_sum(double v) {
    v += dpp_d<0x121>(v);   // row_ror:1
    v += dpp_d<0x122>(v);   // row_ror:2
    v += dpp_d<0x124>(v);   // row_ror:4
    v += dpp_d<0x128>(v);   // row_ror:8
    v += dpp_d<0x142>(v);   // row_bcast15
    v += dpp_d<0x143>(v);   // row_bcast31
    return bcast63(v);
}
// Same for max of nonnegative values (0-injection from bcast steps is safe).
__device__ __forceinline__ double wave_red_max_nn(double v) {
    v = fmax(v, dpp_d<0x121>(v));
    v = fmax(v, dpp_d<0x122>(v));
    v = fmax(v, dpp_d<0x124>(v));
    v = fmax(v, dpp_d<0x128>(v));
    v = fmax(v, dpp_d<0x142>(v));
    v = fmax(v, dpp_d<0x143>(v));
    return bcast63(v);
}

// One wave per batch item. Lane j owns features j, j+64, j+128, j+192.
// Constraints: row0: sum(x)<=C ; lo_i: -x_i<=0 ; hi_i: x_i<=1 ;
// rowA: m.x <= rhs_fair+1 ; rowB: -m.x <= -rhs_fair.
//
// Exact-identity formulation (same fp64 trajectory as the 2.06e-7 round-4
// kernel):
//  * rs scales by (1-alpha) each step  -> rs0/rsA/rsB/rs_lo/rs_hi tracked.
//  * s.dz + z.ds = -rc  =>  musum' = musum(1-a+a*sigma) + a^2*Sum(ds*dz)
//    -> smu known at loop top; group1 = {s11,s12,t1,t2} only.
//  * Sdx = t1 - C1*s11 - C2*s12 ; Smdx = t2 - (C1+C2)*s12  (no reduction).
//  * alpha = min(1, 0.99/max(rmax,0.99)), rmax = max(-ds/s, -dz/z); s-side
//    ratios reuse NR'd i_s; z-side uses raw rcp hoisted into group1.
__global__ __launch_bounds__(64)
void pdipm_kernel(const float* __restrict__ xin,
                  const int* __restrict__ male,
                  float* __restrict__ out) {
    const int b = blockIdx.x;
    const int lane = threadIdx.x;

    double e[4], mf[4], x[4];                 // e = -(EPS*x + p) tracked
    double s_lo[4], s_hi[4], z_lo[4], z_hi[4];
    double rs_lo[4], rs_hi[4];
    double msum_p = 0.0;
    #pragma unroll
    for (int k = 0; k < 4; ++k) {
        const int f = lane + 64 * k;
        const double pv = -(double)xin[b * NF + f];
        mf[k] = (double)male[f];
        msum_p += mf[k];
        e[k] = -pv;                            // x=0 -> e = -p
        x[k] = 0.0;
        s_lo[k] = 1.0; s_hi[k] = 1.0;
        z_lo[k] = 1.0; z_hi[k] = 1.0;
        rs_lo[k] = 1.0;                        // s - x = 1
        rs_hi[k] = 0.0;                        // s + x - 1 = 0
    }
    const double nm = wave_red_sum(msum_p);
    const double rhs_fair = CAPC * nm * (1.0 / 256.0);

    // Scalar-constraint state (wave-uniform).
    double s0 = 1.0, z0 = 1.0, sA = 1.0, zA = 1.0, sB = 1.0, zB = 1.0;
    double rs0 = 1.0 - CAPC;                   // s0 + 0 - C
    double rsA = -rhs_fair;                    // 1 + 0 - (rhs_fair+1)
    double rsB = 1.0 + rhs_fair;               // 1 - 0 + rhs_fair
    double musum = (double)M_CON;              // all s=z=1

    for (int it = 0; it < ITERS; ++it) {
        const double smu = SIGMA * musum * (1.0 / (double)M_CON);

        // ---- wave-uniform scalar precompute (hides under group1) ----
        const double i_s0 = drcp(s0), i_sA = drcp(sA), i_sB = drcp(sB);
        const double i_z0 = drcp_fast(z0), i_zA = drcp_fast(zA), i_zB = drcp_fast(zB);
        const double d0 = z0 * i_s0, dA = zA * i_sA, dB = zB * i_sB;
        const double beta  = d0 * rs0 + smu * i_s0;
        const double gamma = (dA * rsA + smu * i_sA) - (dB * rsB + smu * i_sB);
        const double ia  = drcp(d0);
        const double ibb = drcp(dA + dB);

        // ---- group 1: {s11, s12, t1, t2} + hoisted ratio recips ----
        double i_slo[4], i_shi[4], i_zlo[4], i_zhi[4];
        double d_lo[4], d_hi[4], invD[4], y[4];
        double s11_p = 0.0, s12_p = 0.0, t1_p = 0.0, t2_p = 0.0;
        #pragma unroll
        for (int k = 0; k < 4; ++k) {
            i_slo[k] = drcp(s_lo[k]);
            i_shi[k] = drcp(s_hi[k]);
            i_zlo[k] = drcp_fast(z_lo[k]);     // ratio-only; overlap latency here
            i_zhi[k] = drcp_fast(z_hi[k]);
            d_lo[k] = z_lo[k] * i_slo[k];
            d_hi[k] = z_hi[k] * i_shi[k];
            invD[k] = drcp(EPS_Q + d_lo[k] + d_hi[k]);
            const double rhat = e[k] + d_lo[k] * rs_lo[k] - d_hi[k] * rs_hi[k]
                              + smu * (i_slo[k] - i_shi[k]);
            y[k] = rhat * invD[k];
            s11_p += invD[k];
            s12_p += mf[k] * invD[k];
            t1_p  += y[k];
            t2_p  += mf[k] * y[k];
        }
        const double s11 = wave_red_sum(s11_p);
        const double s12 = wave_red_sum(s12_p);   // == s22 since m is 0/1
        const double t1  = wave_red_sum(t1_p);
        const double t2  = wave_red_sum(t2_p);

        // ---- 2x2 capacitance algebra (closed-form M^-1 1 / M^-1 m) ----
        const double k11 = ia + s11;
        const double k22 = ibb + s12;
        const double i_det = drcp(k11 * k22 - s12 * s12);
        const double c1 = (k22 * t1 - s12 * t2) * i_det;
        const double c2 = (k11 * t2 - s12 * t1) * i_det;
        const double a1 =  ia * k22 * i_det;
        const double a2 = -ia * s12 * i_det;
        const double b1 = -ibb * s12 * i_det;
        const double b2 =  ibb * k11 * i_det;
        const double C1 = c1 + beta * a1 + gamma * b1;
        const double C2 = c2 + beta * a2 + gamma * b2;
        const double C1pC2 = C1 + C2;

        // ---- Sdx/Smdx via identities (no reduction) ----
        const double Sdx  = t1 - C1 * s11 - C2 * s12;
        const double Smdx = t2 - C1pC2 * s12;
        const double ds0 = -rs0 - Sdx;
        const double dsA = -rsA - Smdx;
        const double dsB = -rsB + Smdx;
        const double dz0 = smu * i_s0 - z0 - d0 * ds0;
        const double dzA = smu * i_sA - zA - dA * dsA;
        const double dzB = smu * i_sB - zB - dB * dsB;

        // ---- group 2: per-feature directions, {Sdsdz, rmax} ----
        double dx[4], ds_lo[4], ds_hi[4], dz_lo[4], dz_hi[4];
        double dsdz_p = 0.0;
        double rmax_p = 0.0;
        #pragma unroll
        for (int k = 0; k < 4; ++k) {
            const double C12 = (mf[k] != 0.0) ? C1pC2 : C1;
            dx[k] = fma(-invD[k], C12, y[k]);
            ds_lo[k] = dx[k] - rs_lo[k];           // ds = -rs - G dx, (G dx)_lo=-dx
            ds_hi[k] = -dx[k] - rs_hi[k];
            dz_lo[k] = smu * i_slo[k] - z_lo[k] - d_lo[k] * ds_lo[k];
            dz_hi[k] = smu * i_shi[k] - z_hi[k] - d_hi[k] * ds_hi[k];
            dsdz_p += ds_lo[k] * dz_lo[k] + ds_hi[k] * dz_hi[k];
            const double q1 = -ds_lo[k] * i_slo[k];
            const double q2 = -ds_hi[k] * i_shi[k];
            const double q3 = -dz_lo[k] * i_zlo[k];
            const double q4 = -dz_hi[k] * i_zhi[k];
            rmax_p = fmax(rmax_p, fmax(fmax(q1, q2), fmax(q3, q4)));
        }
        const double Sdsdz_w = wave_red_sum(dsdz_p);
        double rmax = wave_red_max_nn(rmax_p);

        // scalar-constraint ratios (wave-uniform)
        rmax = fmax(rmax, fmax(-ds0 * i_s0, -dz0 * i_z0));
        rmax = fmax(rmax, fmax(-dsA * i_sA, -dzA * i_zA));
        rmax = fmax(rmax, fmax(-dsB * i_sB, -dzB * i_zB));
        const double Sdsdz = Sdsdz_w + ds0 * dz0 + dsA * dzA + dsB * dzB;

        const double alpha = fmin(1.0, 0.99 * drcp_fast(fmax(rmax, 0.99)));
        const double omA = 1.0 - alpha;

        // ---- state update (identities keep rs/musum exact) ----
        #pragma unroll
        for (int k = 0; k < 4; ++k) {
            const double adx = alpha * dx[k];
            x[k] += adx;
            e[k] = fma(-EPS_Q, adx, e[k]);
            s_lo[k] = fma(alpha, ds_lo[k], s_lo[k]);
            s_hi[k] = fma(alpha, ds_hi[k], s_hi[k]);
            z_lo[k] = fma(alpha, dz_lo[k], z_lo[k]);
            z_hi[k] = fma(alpha, dz_hi[k], z_hi[k]);
            rs_lo[k] *= omA;
            rs_hi[k] *= omA;
        }
        s0 = fma(alpha, ds0, s0); z0 = fma(alpha, dz0, z0);
        sA = fma(alpha, dsA, sA); zA = fma(alpha, dzA, zA);
        sB = fma(alpha, dsB, sB); zB = fma(alpha, dzB, zB);
        rs0 *= omA; rsA *= omA; rsB *= omA;
        musum = musum * (1.0 - alpha * (1.0 - SIGMA)) + alpha * alpha * Sdsdz;
    }

    #pragma unroll
    for (int k = 0; k < 4; ++k)
        out[b * NF + lane + 64 * k] = (float)x[k];
}

extern "C" void kernel_launch(void* const* d_in, const int* in_sizes, int n_in,
                              void* d_out, int out_size, void* d_ws, size_t ws_size,
                              hipStream_t stream) {
    const float* xin  = (const float*)d_in[0];   // [64, 256] fp32
    const int*   male = (const int*)d_in[1];     // [256] int32
    float* out = (float*)d_out;                  // [64, 256] fp32
    pdipm_kernel<<<NB, 64, 0, stream>>>(xin, male, out);
}